// Round 9
// baseline (8710.561 us; speedup 1.0000x reference)
//
#include <hip/hip_runtime.h>
#include <hip/hip_fp16.h>
#include <stdint.h>
#include <type_traits>

// ClockworkRNN MI355X round 9 — ABLATION ROUND.
// Real kernel = R8 (verified, absmax 0.0039, scan 1641us) as variant V0.
// V1..V5 are ablations dispatched to ws scratch BEFORE V0 (d_out untouched):
//   V1: no per-step x loads      -> residual global-load exposure
//   V2: no shfl reductions       -> 2x DS-hop chain cost
//   V3: no tanh (linear, bounded)-> tanh cost
//   V4: dot work /4              -> VALU dot-issue cost
//   V5: floor (/16 dots, no loads/shfl/tanh) -> barrier+LDSwrite skeleton
// Read per-dispatch dur_us from rocprof to attribute the ~1920cyc/step.

typedef _Float16 half_t;
typedef _Float16 h2 __attribute__((ext_vector_type(2)));
typedef _Float16 h8 __attribute__((ext_vector_type(8)));
typedef float f4 __attribute__((ext_vector_type(4)));

__device__ __forceinline__ float dot2f(h2 a, h2 b, float c) {
#if defined(__has_builtin)
#if __has_builtin(__builtin_amdgcn_fdot2)
  return __builtin_amdgcn_fdot2(a, b, c, false);
#else
  return c + (float)a[0] * (float)b[0] + (float)a[1] * (float)b[1];
#endif
#else
  return c + (float)a[0] * (float)b[0] + (float)a[1] * (float)b[1];
#endif
}

__device__ __forceinline__ float fast_tanh(float x) {
#if defined(__has_builtin)
#if __has_builtin(__builtin_amdgcn_exp2f) && __has_builtin(__builtin_amdgcn_rcpf)
  float e = __builtin_amdgcn_exp2f(x * 2.885390081777927f);
  return 1.0f - 2.0f * __builtin_amdgcn_rcpf(e + 1.0f);
#else
  float e = __builtin_exp2f(x * 2.885390081777927f);
  return 1.0f - 2.0f / (e + 1.0f);
#endif
#else
  float e = exp2f(x * 2.885390081777927f);
  return 1.0f - 2.0f / (e + 1.0f);
#endif
}

__device__ __forceinline__ float u2f(unsigned short u) {
  return (float)__builtin_bit_cast(half_t, u);
}

__device__ __forceinline__ void wg_barrier_lds() {
  __builtin_amdgcn_sched_barrier(0);
  asm volatile("s_waitcnt lgkmcnt(0)" ::: "memory");
  __builtin_amdgcn_s_barrier();
  __builtin_amdgcn_sched_barrier(0);
}

__device__ __forceinline__ void gl_lds16(const half_t* g, half_t* l) {
  __builtin_amdgcn_global_load_lds(
      (__attribute__((address_space(1))) void*)(void*)g,
      (__attribute__((address_space(3))) void*)(void*)l, 16, 0, 0);
}

// ---------------- cvt kernels (unchanged, verified) ----------------
__global__ void cw_cvt_x(const float* __restrict__ X, half_t* __restrict__ Xh, long n4) {
  long i = (long)blockIdx.x * blockDim.x + threadIdx.x;
  const long stride = (long)gridDim.x * blockDim.x;
  const float4* X4 = (const float4*)X;
  h2* out2 = (h2*)Xh;
  for (; i < n4; i += stride) {
    float4 v = X4[i];
    h2 a; a[0] = (half_t)v.x; a[1] = (half_t)v.y;
    h2 b; b[0] = (half_t)v.z; b[1] = (half_t)v.w;
    out2[2 * i] = a;
    out2[2 * i + 1] = b;
  }
}

__global__ void cw_cvt_wt(const float* __restrict__ W, half_t* __restrict__ WT) {
  int idx = blockIdx.x * 256 + threadIdx.x;  // 131072 total
  int o = idx >> 8, d = idx & 255;
  WT[idx] = (half_t)W[d * 512 + o];
}

// ---------------- x projection (unchanged, verified) ----------------
__global__ __launch_bounds__(256) void cw_xproj(const half_t* __restrict__ Xh,
                                                const half_t* __restrict__ WT,
                                                const float* __restrict__ bias,
                                                half_t* __restrict__ xout) {
  const int mod = blockIdx.y;
  const int Ti = 2048 >> mod;
  const long Mi = (long)64 * Ti;
  const long m0r = (long)blockIdx.x * 256;
  if (m0r >= Mi) return;
  __shared__ alignas(16) half_t Bs[64 * 256];
  __shared__ alignas(16) half_t As[256 * 64];
  const int tid = threadIdx.x;
  const int wv = tid >> 6, l = tid & 63;
  const int lr = l & 15, lk = (l >> 4) * 8;
  const int shf = 11 - mod;

#pragma unroll
  for (int it = 0; it < 8; ++it) {
    int slot = it * 256 + tid;
    int n = slot >> 5, kc = slot & 31;
    gl_lds16(WT + ((mod << 6) + n) * 256 + kc * 8, Bs + slot * 8);
  }

  f4 acc[4][4];
#pragma unroll
  for (int a = 0; a < 4; ++a)
#pragma unroll
    for (int bq = 0; bq < 4; ++bq) acc[a][bq] = f4{0.f, 0.f, 0.f, 0.f};

  for (int kt = 0; kt < 4; ++kt) {
#pragma unroll
    for (int it = 0; it < 8; ++it) {
      int slot = it * 256 + tid;
      int r = slot >> 3, kc = slot & 7;
      long m = m0r + r;
      long g = (m >> shf) * 2048 + ((m & (long)(Ti - 1)) << mod);
      gl_lds16(Xh + g * 256 + kt * 64 + kc * 8, As + slot * 8);
    }
    __syncthreads();
#pragma unroll
    for (int ks = 0; ks < 2; ++ks) {
      h8 af[4], bf[4];
#pragma unroll
      for (int mi = 0; mi < 4; ++mi)
        af[mi] = *(const h8*)&As[(wv * 64 + mi * 16 + lr) * 64 + ks * 32 + lk];
#pragma unroll
      for (int ni = 0; ni < 4; ++ni)
        bf[ni] = *(const h8*)&Bs[(ni * 16 + lr) * 256 + kt * 64 + ks * 32 + lk];
#pragma unroll
      for (int mi = 0; mi < 4; ++mi)
#pragma unroll
        for (int ni = 0; ni < 4; ++ni)
          acc[mi][ni] = __builtin_amdgcn_mfma_f32_16x16x32_f16(af[mi], bf[ni], acc[mi][ni], 0, 0, 0);
    }
    __syncthreads();
  }

  const long xb = 16777216L - (16777216L >> mod);
#pragma unroll
  for (int ni = 0; ni < 4; ++ni) {
    int n = ni * 16 + lr;
    float bv = bias[(mod << 6) + n];
#pragma unroll
    for (int mi = 0; mi < 4; ++mi) {
      f4 cf = acc[mi][ni];
#pragma unroll
      for (int q = 0; q < 4; ++q) {
        long m = m0r + wv * 64 + mi * 16 + (l >> 4) * 4 + q;
        xout[xb + m * 64 + n] = (half_t)(cf[q] + bv);
      }
    }
  }
}

// ---------------- scan round 9 (template ablation) ----------------
#define DOTW(P4, HB, WB, OUTV)                                      \
  do {                                                              \
    const h2* hp = hin2 + (HB) + q * (P4);                          \
    float a0 = 0.f, a1 = 0.f, a2 = 0.f, a3 = 0.f;                   \
    _Pragma("unroll") for (int p = 0; p < (P4) / DDIV; p += 4) {    \
      a0 = dot2f(hp[p + 0], wreg[(WB) + p + 0], a0);                \
      a1 = dot2f(hp[p + 1], wreg[(WB) + p + 1], a1);                \
      a2 = dot2f(hp[p + 2], wreg[(WB) + p + 2], a2);                \
      a3 = dot2f(hp[p + 3], wreg[(WB) + p + 3], a3);                \
    }                                                               \
    OUTV = (a0 + a1) + (a2 + a3);                                   \
  } while (0)

template <int V>
__global__ __launch_bounds__(512, 2) void cw_scan9(
    const half_t* __restrict__ xbuf,
    const float* __restrict__ Wc0, const float* __restrict__ Wc1,
    const float* __restrict__ Wc2, const float* __restrict__ Wc3,
    const float* __restrict__ Wc4, const float* __restrict__ Wc5,
    const float* __restrict__ Wc6, const float* __restrict__ Wc7,
    float* __restrict__ out) {
  constexpr bool DO_LOAD = (V != 1 && V != 5);
  constexpr bool DO_SHFL = (V != 2 && V != 5);
  constexpr bool DO_TANH = (V != 3 && V != 5);
  constexpr int DDIV = (V == 4) ? 4 : (V == 5 ? 16 : 1);

  const int b = blockIdx.x;
  const int tid = threadIdx.x;
  const int wv = tid >> 6;
  const int l = tid & 63;
  const int q = l >> 4;                      // K-chunk 0..3
  const int c = ((wv & 3) << 4) + (l & 15);  // module-local column 0..63
  const bool grpA = (wv < 4);

  __shared__ alignas(16) half_t hbuf[2][512];

  h2 wreg[160];
#pragma unroll
  for (int p = 0; p < 160; ++p) wreg[p] = h2{(half_t)0.f, (half_t)0.f};

  // ---- weight init (all registers; static wreg indices) ----
  if (grpA) {
#pragma unroll
    for (int g = 0; g < 16; ++g) {
      const int gg = (g + 2 * q) & 15;
#pragma unroll
      for (int j = 0; j < 4; ++j) {
        int pr = (q << 6) + gg * 4 + j;
        wreg[4 * g + j] = h2{(half_t)Wc0[(2 * pr) * 64 + c], (half_t)Wc0[(2 * pr + 1) * 64 + c]};
      }
    }
#pragma unroll
    for (int p = 0; p < 40; ++p) {  // m3
      int pr = q * 40 + p;
      wreg[64 + p] = h2{(half_t)Wc3[(2 * pr) * 64 + c], (half_t)Wc3[(2 * pr + 1) * 64 + c]};
    }
#pragma unroll
    for (int p = 0; p < 16; ++p) {  // m6
      int pr = q * 16 + p;
      wreg[104 + p] = h2{(half_t)Wc6[(2 * pr) * 64 + c], (half_t)Wc6[(2 * pr + 1) * 64 + c]};
    }
#pragma unroll
    for (int p = 0; p < 8; ++p) {  // m7
      int pr = q * 8 + p;
      wreg[120 + p] = h2{(half_t)Wc7[(2 * pr) * 64 + c], (half_t)Wc7[(2 * pr + 1) * 64 + c]};
    }
  } else {
#pragma unroll
    for (int p = 0; p < 56; ++p) {  // m1
      int pr = q * 56 + p;
      wreg[p] = h2{(half_t)Wc1[(2 * pr) * 64 + c], (half_t)Wc1[(2 * pr + 1) * 64 + c]};
    }
#pragma unroll
    for (int p = 0; p < 48; ++p) {  // m2
      int pr = q * 48 + p;
      wreg[56 + p] = h2{(half_t)Wc2[(2 * pr) * 64 + c], (half_t)Wc2[(2 * pr + 1) * 64 + c]};
    }
#pragma unroll
    for (int p = 0; p < 32; ++p) {  // m4
      int pr = q * 32 + p;
      wreg[104 + p] = h2{(half_t)Wc4[(2 * pr) * 64 + c], (half_t)Wc4[(2 * pr + 1) * 64 + c]};
    }
#pragma unroll
    for (int p = 0; p < 24; ++p) {  // m5
      int pr = q * 24 + p;
      wreg[136 + p] = h2{(half_t)Wc5[(2 * pr) * 64 + c], (half_t)Wc5[(2 * pr + 1) * 64 + c]};
    }
  }

  hbuf[0][tid] = (half_t)0.f;
  hbuf[1][tid] = (half_t)0.f;

  // ---- x pointers as RAW u16 ----
  const unsigned short *xpP, *xpQ, *xpR, *xpS;
  const unsigned short* xb16 = (const unsigned short*)xbuf;
  if (grpA) {
    xpP = xb16 + ((long)b << 17) + c;              // m0
    xpQ = xb16 + 14680064L + ((long)b << 14) + c;  // m3
    xpR = xb16 + 16515072L + ((long)b << 11) + c;  // m6
    xpS = xb16 + 16646144L + ((long)b << 10) + c;  // m7
  } else {
    xpP = xb16 + 8388608L + ((long)b << 16) + c;   // m1
    xpQ = xb16 + 12582912L + ((long)b << 15) + c;  // m2
    xpR = xb16 + 15728640L + ((long)b << 13) + c;  // m4
    xpS = xb16 + 16252928L + ((long)b << 12) + c;  // m5
  }

  float hsP = 0.f, hsQ = 0.f, hsR = 0.f, hsS = 0.f;
  unsigned short xu0 = 0, xu1 = 0, xu2 = 0, xu3 = 0;
  unsigned short xuQ = 0, xuR = 0, xuS = 0;
  if (l < 16) {
    if (grpA) {
      xu0 = xpP[0];
      xu1 = xpP[64];
      xu2 = xpP[128];
      xu3 = xpP[192];
    } else {
      xu0 = xpP[0];
      xu1 = xpP[64];
    }
    xuQ = xpQ[0];
    xuR = xpR[0];
    xuS = xpS[0];
  }
  __syncthreads();

  // activation helpers (ablation-aware, dataflow preserved)
  auto act = [&](float s) {
    if constexpr (DO_TANH) return fast_tanh(s);
    else return s * 0.125f;
  };
  auto red = [&](float v) {
    if constexpr (DO_SHFL) {
      v += __shfl_xor(v, 16);
      v += __shfl_xor(v, 32);
    }
    return v;
  };

  auto step = [&](auto offc, int t, const half_t* hin, half_t* hout) {
    constexpr int OFF = decltype(offc)::value;
    const h2* hin2 = (const h2*)hin;
    if (grpA) {
      float v0;
      {
        const h2* hp = hin2 + (q << 6);
        float a0 = 0.f, a1 = 0.f, a2 = 0.f, a3 = 0.f;
#pragma unroll
        for (int g = 0; g < 16 / DDIV; ++g) {
          const int gg = (g + 2 * q) & 15;
          a0 = dot2f(hp[gg * 4 + 0], wreg[4 * g + 0], a0);
          a1 = dot2f(hp[gg * 4 + 1], wreg[4 * g + 1], a1);
          a2 = dot2f(hp[gg * 4 + 2], wreg[4 * g + 2], a2);
          a3 = dot2f(hp[gg * 4 + 3], wreg[4 * g + 3], a3);
        }
        v0 = (a0 + a1) + (a2 + a3);
      }
      v0 = red(v0);
      const bool u3 = (OFF == 0) && ((t & 7) == 0);
      const bool u6 = (OFF == 0) && ((t & 63) == 0);
      const bool u7 = (OFF == 0) && ((t & 127) == 0);
      float v3 = 0.f, v6 = 0.f, v7 = 0.f;
      if (u3) { DOTW(40, 96, 64, v3); v3 = red(v3); }
      if (u6) { DOTW(16, 192, 104, v6); v6 = red(v6); }
      if (u7) { DOTW(8, 224, 120, v7); v7 = red(v7); }
      if (l < 16) {
        float xv;
        if constexpr (OFF == 0) xv = u2f(xu0);
        else if constexpr (OFF == 1) xv = u2f(xu1);
        else if constexpr (OFF == 2) xv = u2f(xu2);
        else xv = u2f(xu3);
        hsP = act(v0 + xv);
        hout[c] = (half_t)hsP;
        if constexpr (DO_LOAD) {
          int tn = t + OFF + 4;
          if (tn < 2048) {
            unsigned short nv = xpP[(long)tn << 6];
            if constexpr (OFF == 0) xu0 = nv;
            else if constexpr (OFF == 1) xu1 = nv;
            else if constexpr (OFF == 2) xu2 = nv;
            else xu3 = nv;
          }
        }
        if (u3) {
          hsQ = act(v3 + u2f(xuQ));
          if constexpr (DO_LOAD) {
            int ni = (t >> 3) + 1;
            if (ni < 256) xuQ = xpQ[(long)ni << 6];
          }
        } else {
          hsQ = act(hsQ);
        }
        hout[192 + c] = (half_t)hsQ;
        if (u6) {
          hsR = act(v6 + u2f(xuR));
          if constexpr (DO_LOAD) {
            int ni = (t >> 6) + 1;
            if (ni < 32) xuR = xpR[(long)ni << 6];
          }
        } else {
          hsR = act(hsR);
        }
        hout[384 + c] = (half_t)hsR;
        if (u7) {
          hsS = act(v7 + u2f(xuS));
          if constexpr (DO_LOAD) {
            int ni = (t >> 7) + 1;
            if (ni < 16) xuS = xpS[(long)ni << 6];
          }
        } else {
          hsS = act(hsS);
        }
        hout[448 + c] = (half_t)hsS;
      }
    } else {
      const bool u4 = (OFF == 0) && ((t & 15) == 0);
      const bool u5 = (OFF == 0) && ((t & 31) == 0);
      float v1 = 0.f, v2 = 0.f, v4 = 0.f, v5 = 0.f;
      if constexpr ((OFF & 1) == 0) { DOTW(56, 32, 0, v1); v1 = red(v1); }
      if constexpr (OFF == 0) { DOTW(48, 64, 56, v2); v2 = red(v2); }
      if (u4) { DOTW(32, 128, 104, v4); v4 = red(v4); }
      if (u5) { DOTW(24, 160, 136, v5); v5 = red(v5); }
      if (l < 16) {
        if constexpr ((OFF & 1) == 0) {
          float xv = (OFF == 0) ? u2f(xu0) : u2f(xu1);
          hsP = act(v1 + xv);
          if constexpr (DO_LOAD) {
            int rn = ((t + OFF) >> 1) + 2;
            if (rn < 1024) {
              unsigned short nv = xpP[(long)rn << 6];
              if constexpr (OFF == 0) xu0 = nv;
              else xu1 = nv;
            }
          }
        } else {
          hsP = act(hsP);
        }
        hout[64 + c] = (half_t)hsP;
        if constexpr (OFF == 0) {
          hsQ = act(v2 + u2f(xuQ));
          if constexpr (DO_LOAD) {
            int ni = (t >> 2) + 1;
            if (ni < 512) xuQ = xpQ[(long)ni << 6];
          }
        } else {
          hsQ = act(hsQ);
        }
        hout[128 + c] = (half_t)hsQ;
        if (u4) {
          hsR = act(v4 + u2f(xuR));
          if constexpr (DO_LOAD) {
            int ni = (t >> 4) + 1;
            if (ni < 128) xuR = xpR[(long)ni << 6];
          }
        } else {
          hsR = act(hsR);
        }
        hout[256 + c] = (half_t)hsR;
        if (u5) {
          hsS = act(v5 + u2f(xuS));
          if constexpr (DO_LOAD) {
            int ni = (t >> 5) + 1;
            if (ni < 64) xuS = xpS[(long)ni << 6];
          }
        } else {
          hsS = act(hsS);
        }
        hout[320 + c] = (half_t)hsS;
      }
    }
    wg_barrier_lds();
  };

  for (int t = 0; t < 2048; t += 4) {
    step(std::integral_constant<int, 0>{}, t, hbuf[0], hbuf[1]);
    step(std::integral_constant<int, 1>{}, t, hbuf[1], hbuf[0]);
    step(std::integral_constant<int, 2>{}, t, hbuf[0], hbuf[1]);
    step(std::integral_constant<int, 3>{}, t, hbuf[1], hbuf[0]);
  }

  float* ob = out + ((long)b << 9);
  if (l < 16) {
    if (grpA) {
      ob[c] = hsP;
      ob[192 + c] = hsQ;
      ob[384 + c] = hsR;
      ob[448 + c] = hsS;
    } else {
      ob[64 + c] = hsP;
      ob[128 + c] = hsQ;
      ob[256 + c] = hsR;
      ob[320 + c] = hsS;
    }
  }
}

// ---------------- launcher ----------------
extern "C" void kernel_launch(void* const* d_in, const int* in_sizes, int n_in,
                              void* d_out, int out_size, void* d_ws, size_t ws_size,
                              hipStream_t stream) {
  const float* X = (const float*)d_in[0];
  const float* W = (const float*)d_in[1];
  const float* bias = (const float*)d_in[2];
  const float* Wc0 = (const float*)d_in[3];
  const float* Wc1 = (const float*)d_in[4];
  const float* Wc2 = (const float*)d_in[5];
  const float* Wc3 = (const float*)d_in[6];
  const float* Wc4 = (const float*)d_in[7];
  const float* Wc5 = (const float*)d_in[8];
  const float* Wc6 = (const float*)d_in[9];
  const float* Wc7 = (const float*)d_in[10];
  float* out = (float*)d_out;

  half_t* Xh = (half_t*)d_ws;                       // 67,108,864 B (scratch-out reuse ok)
  half_t* WT = (half_t*)((char*)d_ws + 67108864);   //    262,144 B
  half_t* xbuf = (half_t*)((char*)d_ws + 67371008); // 33,423,360 B
  float* scr = (float*)d_ws;  // ablation dummy out (Xh region; consumed before scans)

  cw_cvt_x<<<4096, 256, 0, stream>>>(X, Xh, 8388608L);
  cw_cvt_wt<<<512, 256, 0, stream>>>(W, WT);
  dim3 g(512, 8);
  cw_xproj<<<g, 256, 0, stream>>>(Xh, WT, bias, xbuf);
  // ablations (scratch out), then the real kernel (d_out)
  cw_scan9<5><<<64, 512, 0, stream>>>(xbuf, Wc0, Wc1, Wc2, Wc3, Wc4, Wc5, Wc6, Wc7, scr);
  cw_scan9<4><<<64, 512, 0, stream>>>(xbuf, Wc0, Wc1, Wc2, Wc3, Wc4, Wc5, Wc6, Wc7, scr);
  cw_scan9<3><<<64, 512, 0, stream>>>(xbuf, Wc0, Wc1, Wc2, Wc3, Wc4, Wc5, Wc6, Wc7, scr);
  cw_scan9<2><<<64, 512, 0, stream>>>(xbuf, Wc0, Wc1, Wc2, Wc3, Wc4, Wc5, Wc6, Wc7, scr);
  cw_scan9<1><<<64, 512, 0, stream>>>(xbuf, Wc0, Wc1, Wc2, Wc3, Wc4, Wc5, Wc6, Wc7, scr);
  cw_scan9<0><<<64, 512, 0, stream>>>(xbuf, Wc0, Wc1, Wc2, Wc3, Wc4, Wc5, Wc6, Wc7, out);
}

// Round 10
// 3268.118 us; speedup vs baseline: 2.6653x; 2.6653x over previous
//
#include <hip/hip_runtime.h>
#include <hip/hip_fp16.h>
#include <stdint.h>
#include <type_traits>

// ClockworkRNN MI355X round 10.
// R8 numerics (verified) + two chain cuts:
//  (1) red3: 3 INDEPENDENT shfl_xor(16/32/48) gathers (one DS-latency hop)
//      instead of 2 dependent butterfly shfls (two hops).
//  (2) owner redistribution: subgroup sg=l>>4 owns ONE module
//      (grpA: sg0=m0 sg1=m3 sg2=m6 sg3=m7; grpB: sg0=m1 sg1=m2 sg2=m4 sg3=m5)
//      -> owner phase = 1 tanh + 1 LDS write per lane (was 4+4 on lanes<16).
// Plus V5 floor probe at 4x steps (8192) so it tops the rocprof table:
// floor-per-step = dur/4. V5 writes scratch; V0 writes d_out.
// ws layout (bytes): [0, 67108864) X f16 | [67108864, 67371008) W^T f16 |
//                    [67371008, 100794368) compact x f16.

typedef _Float16 half_t;
typedef _Float16 h2 __attribute__((ext_vector_type(2)));
typedef _Float16 h8 __attribute__((ext_vector_type(8)));
typedef float f4 __attribute__((ext_vector_type(4)));

__device__ __forceinline__ float dot2f(h2 a, h2 b, float c) {
#if defined(__has_builtin)
#if __has_builtin(__builtin_amdgcn_fdot2)
  return __builtin_amdgcn_fdot2(a, b, c, false);
#else
  return c + (float)a[0] * (float)b[0] + (float)a[1] * (float)b[1];
#endif
#else
  return c + (float)a[0] * (float)b[0] + (float)a[1] * (float)b[1];
#endif
}

__device__ __forceinline__ float fast_tanh(float x) {
#if defined(__has_builtin)
#if __has_builtin(__builtin_amdgcn_exp2f) && __has_builtin(__builtin_amdgcn_rcpf)
  float e = __builtin_amdgcn_exp2f(x * 2.885390081777927f);
  return 1.0f - 2.0f * __builtin_amdgcn_rcpf(e + 1.0f);
#else
  float e = __builtin_exp2f(x * 2.885390081777927f);
  return 1.0f - 2.0f / (e + 1.0f);
#endif
#else
  float e = exp2f(x * 2.885390081777927f);
  return 1.0f - 2.0f / (e + 1.0f);
#endif
}

__device__ __forceinline__ float u2f(unsigned short u) {
  return (float)__builtin_bit_cast(half_t, u);
}

// 4-way reduce over lane groups {l, l^16, l^32, l^48}: three INDEPENDENT
// gathers (latencies overlap) + 3 adds -- one DS hop on the chain, not two.
__device__ __forceinline__ float red3(float v) {
  float a = __shfl_xor(v, 16);
  float b = __shfl_xor(v, 32);
  float d = __shfl_xor(v, 48);
  return (v + a) + (b + d);
}

// Relaxed workgroup barrier: orders LDS (lgkm) but leaves global loads in flight.
__device__ __forceinline__ void wg_barrier_lds() {
  __builtin_amdgcn_sched_barrier(0);
  asm volatile("s_waitcnt lgkmcnt(0)" ::: "memory");
  __builtin_amdgcn_s_barrier();
  __builtin_amdgcn_sched_barrier(0);
}

__device__ __forceinline__ void gl_lds16(const half_t* g, half_t* l) {
  __builtin_amdgcn_global_load_lds(
      (__attribute__((address_space(1))) void*)(void*)g,
      (__attribute__((address_space(3))) void*)(void*)l, 16, 0, 0);
}

// ---------------- cvt kernels (unchanged, verified) ----------------
__global__ void cw_cvt_x(const float* __restrict__ X, half_t* __restrict__ Xh, long n4) {
  long i = (long)blockIdx.x * blockDim.x + threadIdx.x;
  const long stride = (long)gridDim.x * blockDim.x;
  const float4* X4 = (const float4*)X;
  h2* out2 = (h2*)Xh;
  for (; i < n4; i += stride) {
    float4 v = X4[i];
    h2 a; a[0] = (half_t)v.x; a[1] = (half_t)v.y;
    h2 b; b[0] = (half_t)v.z; b[1] = (half_t)v.w;
    out2[2 * i] = a;
    out2[2 * i + 1] = b;
  }
}

__global__ void cw_cvt_wt(const float* __restrict__ W, half_t* __restrict__ WT) {
  int idx = blockIdx.x * 256 + threadIdx.x;  // 131072 total
  int o = idx >> 8, d = idx & 255;
  WT[idx] = (half_t)W[d * 512 + o];
}

// ---------------- x projection (unchanged, verified) ----------------
__global__ __launch_bounds__(256) void cw_xproj(const half_t* __restrict__ Xh,
                                                const half_t* __restrict__ WT,
                                                const float* __restrict__ bias,
                                                half_t* __restrict__ xout) {
  const int mod = blockIdx.y;
  const int Ti = 2048 >> mod;
  const long Mi = (long)64 * Ti;
  const long m0r = (long)blockIdx.x * 256;
  if (m0r >= Mi) return;
  __shared__ alignas(16) half_t Bs[64 * 256];
  __shared__ alignas(16) half_t As[256 * 64];
  const int tid = threadIdx.x;
  const int wv = tid >> 6, l = tid & 63;
  const int lr = l & 15, lk = (l >> 4) * 8;
  const int shf = 11 - mod;

#pragma unroll
  for (int it = 0; it < 8; ++it) {
    int slot = it * 256 + tid;
    int n = slot >> 5, kc = slot & 31;
    gl_lds16(WT + ((mod << 6) + n) * 256 + kc * 8, Bs + slot * 8);
  }

  f4 acc[4][4];
#pragma unroll
  for (int a = 0; a < 4; ++a)
#pragma unroll
    for (int bq = 0; bq < 4; ++bq) acc[a][bq] = f4{0.f, 0.f, 0.f, 0.f};

  for (int kt = 0; kt < 4; ++kt) {
#pragma unroll
    for (int it = 0; it < 8; ++it) {
      int slot = it * 256 + tid;
      int r = slot >> 3, kc = slot & 7;
      long m = m0r + r;
      long g = (m >> shf) * 2048 + ((m & (long)(Ti - 1)) << mod);
      gl_lds16(Xh + g * 256 + kt * 64 + kc * 8, As + slot * 8);
    }
    __syncthreads();
#pragma unroll
    for (int ks = 0; ks < 2; ++ks) {
      h8 af[4], bf[4];
#pragma unroll
      for (int mi = 0; mi < 4; ++mi)
        af[mi] = *(const h8*)&As[(wv * 64 + mi * 16 + lr) * 64 + ks * 32 + lk];
#pragma unroll
      for (int ni = 0; ni < 4; ++ni)
        bf[ni] = *(const h8*)&Bs[(ni * 16 + lr) * 256 + kt * 64 + ks * 32 + lk];
#pragma unroll
      for (int mi = 0; mi < 4; ++mi)
#pragma unroll
        for (int ni = 0; ni < 4; ++ni)
          acc[mi][ni] = __builtin_amdgcn_mfma_f32_16x16x32_f16(af[mi], bf[ni], acc[mi][ni], 0, 0, 0);
    }
    __syncthreads();
  }

  const long xb = 16777216L - (16777216L >> mod);
#pragma unroll
  for (int ni = 0; ni < 4; ++ni) {
    int n = ni * 16 + lr;
    float bv = bias[(mod << 6) + n];
#pragma unroll
    for (int mi = 0; mi < 4; ++mi) {
      f4 cf = acc[mi][ni];
#pragma unroll
      for (int q = 0; q < 4; ++q) {
        long m = m0r + wv * 64 + mi * 16 + (l >> 4) * 4 + q;
        xout[xb + m * 64 + n] = (half_t)(cf[q] + bv);
      }
    }
  }
}

// ---------------- scan round 10 ----------------
#define DOTW(P4, HB, WB, OUTV)                                      \
  do {                                                              \
    const h2* hp = hin2 + (HB) + q * (P4);                          \
    float a0 = 0.f, a1 = 0.f, a2 = 0.f, a3 = 0.f;                   \
    _Pragma("unroll") for (int p = 0; p < (P4) / DDIV; p += 4) {    \
      a0 = dot2f(hp[p + 0], wreg[(WB) + p + 0], a0);                \
      a1 = dot2f(hp[p + 1], wreg[(WB) + p + 1], a1);                \
      a2 = dot2f(hp[p + 2], wreg[(WB) + p + 2], a2);                \
      a3 = dot2f(hp[p + 3], wreg[(WB) + p + 3], a3);                \
    }                                                               \
    OUTV = (a0 + a1) + (a2 + a3);                                   \
  } while (0)

template <int V>
__global__ __launch_bounds__(512, 2) void cw_scan10(
    const half_t* __restrict__ xbuf,
    const float* __restrict__ Wc0, const float* __restrict__ Wc1,
    const float* __restrict__ Wc2, const float* __restrict__ Wc3,
    const float* __restrict__ Wc4, const float* __restrict__ Wc5,
    const float* __restrict__ Wc6, const float* __restrict__ Wc7,
    float* __restrict__ out) {
  constexpr bool FLOOR = (V == 5);
  constexpr int NT = FLOOR ? 8192 : 2048;  // floor probe runs 4x steps
  constexpr int DDIV = FLOOR ? 16 : 1;

  const int b = blockIdx.x;
  const int tid = threadIdx.x;
  const int wv = tid >> 6;
  const int l = tid & 63;
  const int q = l >> 4;                      // K-chunk 0..3  (== owner subgroup sg)
  const int sg = q;
  const int c = ((wv & 3) << 4) + (l & 15);  // module-local column 0..63
  const bool grpA = (wv < 4);

  __shared__ alignas(16) half_t hbuf[2][512];

  h2 wreg[160];
#pragma unroll
  for (int p = 0; p < 160; ++p) wreg[p] = h2{(half_t)0.f, (half_t)0.f};

  // ---- weight init (identical to R8, verified) ----
  if (grpA) {
#pragma unroll
    for (int g = 0; g < 16; ++g) {
      const int gg = (g + 2 * q) & 15;
#pragma unroll
      for (int j = 0; j < 4; ++j) {
        int pr = (q << 6) + gg * 4 + j;
        wreg[4 * g + j] = h2{(half_t)Wc0[(2 * pr) * 64 + c], (half_t)Wc0[(2 * pr + 1) * 64 + c]};
      }
    }
#pragma unroll
    for (int p = 0; p < 40; ++p) {  // m3
      int pr = q * 40 + p;
      wreg[64 + p] = h2{(half_t)Wc3[(2 * pr) * 64 + c], (half_t)Wc3[(2 * pr + 1) * 64 + c]};
    }
#pragma unroll
    for (int p = 0; p < 16; ++p) {  // m6
      int pr = q * 16 + p;
      wreg[104 + p] = h2{(half_t)Wc6[(2 * pr) * 64 + c], (half_t)Wc6[(2 * pr + 1) * 64 + c]};
    }
#pragma unroll
    for (int p = 0; p < 8; ++p) {  // m7
      int pr = q * 8 + p;
      wreg[120 + p] = h2{(half_t)Wc7[(2 * pr) * 64 + c], (half_t)Wc7[(2 * pr + 1) * 64 + c]};
    }
  } else {
#pragma unroll
    for (int p = 0; p < 56; ++p) {  // m1
      int pr = q * 56 + p;
      wreg[p] = h2{(half_t)Wc1[(2 * pr) * 64 + c], (half_t)Wc1[(2 * pr + 1) * 64 + c]};
    }
#pragma unroll
    for (int p = 0; p < 48; ++p) {  // m2
      int pr = q * 48 + p;
      wreg[56 + p] = h2{(half_t)Wc2[(2 * pr) * 64 + c], (half_t)Wc2[(2 * pr + 1) * 64 + c]};
    }
#pragma unroll
    for (int p = 0; p < 32; ++p) {  // m4
      int pr = q * 32 + p;
      wreg[104 + p] = h2{(half_t)Wc4[(2 * pr) * 64 + c], (half_t)Wc4[(2 * pr + 1) * 64 + c]};
    }
#pragma unroll
    for (int p = 0; p < 24; ++p) {  // m5
      int pr = q * 24 + p;
      wreg[136 + p] = h2{(half_t)Wc5[(2 * pr) * 64 + c], (half_t)Wc5[(2 * pr + 1) * 64 + c]};
    }
  }

  hbuf[0][tid] = (half_t)0.f;
  hbuf[1][tid] = (half_t)0.f;

  // ---- per-subgroup x pointer + owner constants ----
  const unsigned short* xb16 = (const unsigned short*)xbuf;
  const unsigned short* xpP;  // sg0's module (m0 or m1)
  const unsigned short* xpO;  // sg1..3's module
  int sshift, slim, soff;
  if (grpA) {
    xpP = xb16 + ((long)b << 17) + c;  // m0
    if (sg == 1) { xpO = xb16 + 14680064L + ((long)b << 14) + c; sshift = 3; slim = 256; soff = 192; }       // m3
    else if (sg == 2) { xpO = xb16 + 16515072L + ((long)b << 11) + c; sshift = 6; slim = 32; soff = 384; }   // m6
    else { xpO = xb16 + 16646144L + ((long)b << 10) + c; sshift = 7; slim = 16; soff = 448; }                // m7
  } else {
    xpP = xb16 + 8388608L + ((long)b << 16) + c;  // m1
    if (sg == 1) { xpO = xb16 + 12582912L + ((long)b << 15) + c; sshift = 2; slim = 512; soff = 128; }       // m2
    else if (sg == 2) { xpO = xb16 + 15728640L + ((long)b << 13) + c; sshift = 4; slim = 128; soff = 256; }  // m4
    else { xpO = xb16 + 16252928L + ((long)b << 12) + c; sshift = 5; slim = 64; soff = 320; }                // m5
  }

  float hsP = 0.f;
  unsigned short xu0 = 0, xu1 = 0, xu2 = 0, xu3 = 0, xuB = 0;
  if (sg == 0) {
    if (grpA) {
      xu0 = xpP[0];
      xu1 = xpP[64];
      xu2 = xpP[128];
      xu3 = xpP[192];
    } else {
      xu0 = xpP[0];   // m1 row 0 (t=0)
      xu1 = xpP[64];  // m1 row 1 (t=2)
    }
  } else {
    xuB = xpO[0];
  }
  __syncthreads();

  auto act = [&](float s) {
    if constexpr (FLOOR) return s * 0.125f;
    else return fast_tanh(s);
  };
  auto red = [&](float v) {
    if constexpr (FLOOR) return v;
    else return red3(v);
  };

  auto step = [&](auto offc, int t, const half_t* hin, half_t* hout) {
    constexpr int OFF = decltype(offc)::value;
    const h2* hin2 = (const h2*)hin;
    if (grpA) {
      // ---- m0 dot every step (rotated reads, static wreg — R4-verified) ----
      float v0;
      {
        const h2* hp = hin2 + (q << 6);
        float a0 = 0.f, a1 = 0.f, a2 = 0.f, a3 = 0.f;
#pragma unroll
        for (int g = 0; g < 16 / DDIV; ++g) {
          const int gg = (g + 2 * q) & 15;  // runtime LDS index only
          a0 = dot2f(hp[gg * 4 + 0], wreg[4 * g + 0], a0);
          a1 = dot2f(hp[gg * 4 + 1], wreg[4 * g + 1], a1);
          a2 = dot2f(hp[gg * 4 + 2], wreg[4 * g + 2], a2);
          a3 = dot2f(hp[gg * 4 + 3], wreg[4 * g + 3], a3);
        }
        v0 = (a0 + a1) + (a2 + a3);
      }
      v0 = red(v0);
      const bool u3 = (OFF == 0) && ((t & 7) == 0);
      const bool u6 = (OFF == 0) && ((t & 63) == 0);
      const bool u7 = (OFF == 0) && ((t & 127) == 0);
      float vA = 0.f, vB = 0.f, vC = 0.f;
      if (u3) { DOTW(40, 96, 64, vA); vA = red(vA); }
      if (u6) { DOTW(16, 192, 104, vB); vB = red(vB); }
      if (u7) { DOTW(8, 224, 120, vC); vC = red(vC); }
      if (sg == 0) {
        // m0 owner: update every step
        float xv;
        if constexpr (OFF == 0) xv = u2f(xu0);
        else if constexpr (OFF == 1) xv = u2f(xu1);
        else if constexpr (OFF == 2) xv = u2f(xu2);
        else xv = u2f(xu3);
        hsP = act(v0 + xv);
        hout[c] = (half_t)hsP;
        if constexpr (!FLOOR) {
          int tn = t + OFF + 4;
          if (tn < 2048) {
            unsigned short nv = xpP[(long)tn << 6];
            if constexpr (OFF == 0) xu0 = nv;
            else if constexpr (OFF == 1) xu1 = nv;
            else if constexpr (OFF == 2) xu2 = nv;
            else xu3 = nv;
          }
        }
      } else {
        // slow owner (m3/m6/m7): branchless update-or-chain
        bool upd = (OFF == 0) && ((t & ((1 << sshift) - 1)) == 0);
        float vsel = (sg == 1) ? vA : ((sg == 2) ? vB : vC);
        float s = upd ? (vsel + u2f(xuB)) : hsP;
        hsP = act(s);
        hout[soff + c] = (half_t)hsP;
        if constexpr (!FLOOR) {
          if (upd) {
            int ni = (t >> sshift) + 1;
            if (ni < slim) xuB = xpO[(long)ni << 6];
          }
        }
      }
    } else {
      const bool u4 = (OFF == 0) && ((t & 15) == 0);
      const bool u5 = (OFF == 0) && ((t & 31) == 0);
      float v1 = 0.f, vA = 0.f, vB = 0.f, vC = 0.f;
      if constexpr ((OFF & 1) == 0) { DOTW(56, 32, 0, v1); v1 = red(v1); }
      if constexpr (OFF == 0) { DOTW(48, 64, 56, vA); vA = red(vA); }
      if (u4) { DOTW(32, 128, 104, vB); vB = red(vB); }
      if (u5) { DOTW(24, 160, 136, vC); vC = red(vC); }
      if (sg == 0) {
        // m1 owner: update on even t
        if constexpr ((OFF & 1) == 0) {
          float xv = (OFF == 0) ? u2f(xu0) : u2f(xu1);
          hsP = act(v1 + xv);
          if constexpr (!FLOOR) {
            int rn = ((t + OFF) >> 1) + 2;
            if (rn < 1024) {
              unsigned short nv = xpP[(long)rn << 6];
              if constexpr (OFF == 0) xu0 = nv;
              else xu1 = nv;
            }
          }
        } else {
          hsP = act(hsP);
        }
        hout[64 + c] = (half_t)hsP;
      } else {
        // slow owner (m2/m4/m5): branchless update-or-chain
        bool upd = (OFF == 0) && ((t & ((1 << sshift) - 1)) == 0);
        float vsel = (sg == 1) ? vA : ((sg == 2) ? vB : vC);
        float s = upd ? (vsel + u2f(xuB)) : hsP;
        hsP = act(s);
        hout[soff + c] = (half_t)hsP;
        if constexpr (!FLOOR) {
          if (upd) {
            int ni = (t >> sshift) + 1;
            if (ni < slim) xuB = xpO[(long)ni << 6];
          }
        }
      }
    }
    wg_barrier_lds();
  };

  for (int t = 0; t < NT; t += 4) {
    step(std::integral_constant<int, 0>{}, t, hbuf[0], hbuf[1]);
    step(std::integral_constant<int, 1>{}, t, hbuf[1], hbuf[0]);
    step(std::integral_constant<int, 2>{}, t, hbuf[0], hbuf[1]);
    step(std::integral_constant<int, 3>{}, t, hbuf[1], hbuf[0]);
  }

  // ---- output: each subgroup writes its module's column ----
  float* ob = out + ((long)b << 9);
  if (grpA) {
    if (sg == 0) ob[c] = hsP;
    else ob[soff + c] = hsP;
  } else {
    if (sg == 0) ob[64 + c] = hsP;
    else ob[soff + c] = hsP;
  }
}

// ---------------- launcher ----------------
extern "C" void kernel_launch(void* const* d_in, const int* in_sizes, int n_in,
                              void* d_out, int out_size, void* d_ws, size_t ws_size,
                              hipStream_t stream) {
  const float* X = (const float*)d_in[0];
  const float* W = (const float*)d_in[1];
  const float* bias = (const float*)d_in[2];
  const float* Wc0 = (const float*)d_in[3];
  const float* Wc1 = (const float*)d_in[4];
  const float* Wc2 = (const float*)d_in[5];
  const float* Wc3 = (const float*)d_in[6];
  const float* Wc4 = (const float*)d_in[7];
  const float* Wc5 = (const float*)d_in[8];
  const float* Wc6 = (const float*)d_in[9];
  const float* Wc7 = (const float*)d_in[10];
  float* out = (float*)d_out;

  half_t* Xh = (half_t*)d_ws;                       // 67,108,864 B
  half_t* WT = (half_t*)((char*)d_ws + 67108864);   //    262,144 B
  half_t* xbuf = (half_t*)((char*)d_ws + 67371008); // 33,423,360 B
  float* scr = (float*)d_ws;  // floor-probe dummy out (Xh region; consumed already)

  cw_cvt_x<<<4096, 256, 0, stream>>>(X, Xh, 8388608L);
  cw_cvt_wt<<<512, 256, 0, stream>>>(W, WT);
  dim3 g(512, 8);
  cw_xproj<<<g, 256, 0, stream>>>(Xh, WT, bias, xbuf);
  cw_scan10<5><<<64, 512, 0, stream>>>(xbuf, Wc0, Wc1, Wc2, Wc3, Wc4, Wc5, Wc6, Wc7, scr);
  cw_scan10<0><<<64, 512, 0, stream>>>(xbuf, Wc0, Wc1, Wc2, Wc3, Wc4, Wc5, Wc6, Wc7, out);
}

// Round 11
// 1523.496 us; speedup vs baseline: 5.7175x; 2.1451x over previous
//
#include <hip/hip_runtime.h>
#include <hip/hip_fp16.h>
#include <stdint.h>
#include <type_traits>

// ClockworkRNN MI355X round 11.
// LDS-op-count halving: each module on 2 waves, 2 cols/lane (each h2 read
// feeds 2 dot2), 4-way K-split + red3, every lane owns exactly 1 column.
// Wave pairs: {0,1}=m0+m6 {2,3}=m1+m5 {4,5}=m2+m4 {6,7}=m3+m7.
// Evidence: R10 V5 floor <475cyc/step; residual ~1400cyc matches ~107
// wave-ds_read_b128/step on the single LDS pipe; this cuts it to ~56.
// ws layout (bytes): [0, 67108864) X f16 | [67108864, 67371008) W^T f16 |
//                    [67371008, 100794368) compact x f16.

typedef _Float16 half_t;
typedef _Float16 h2 __attribute__((ext_vector_type(2)));
typedef _Float16 h8 __attribute__((ext_vector_type(8)));
typedef float f4 __attribute__((ext_vector_type(4)));

__device__ __forceinline__ float dot2f(h2 a, h2 b, float c) {
#if defined(__has_builtin)
#if __has_builtin(__builtin_amdgcn_fdot2)
  return __builtin_amdgcn_fdot2(a, b, c, false);
#else
  return c + (float)a[0] * (float)b[0] + (float)a[1] * (float)b[1];
#endif
#else
  return c + (float)a[0] * (float)b[0] + (float)a[1] * (float)b[1];
#endif
}

__device__ __forceinline__ float fast_tanh(float x) {
#if defined(__has_builtin)
#if __has_builtin(__builtin_amdgcn_exp2f) && __has_builtin(__builtin_amdgcn_rcpf)
  float e = __builtin_amdgcn_exp2f(x * 2.885390081777927f);
  return 1.0f - 2.0f * __builtin_amdgcn_rcpf(e + 1.0f);
#else
  float e = __builtin_exp2f(x * 2.885390081777927f);
  return 1.0f - 2.0f / (e + 1.0f);
#endif
#else
  float e = exp2f(x * 2.885390081777927f);
  return 1.0f - 2.0f / (e + 1.0f);
#endif
}

__device__ __forceinline__ float u2f(unsigned short u) {
  return (float)__builtin_bit_cast(half_t, u);
}

// 4-way reduce over {l, l^16, l^32, l^48}: 3 independent gathers, 1 DS hop.
__device__ __forceinline__ float red3(float v) {
  float a = __shfl_xor(v, 16);
  float b = __shfl_xor(v, 32);
  float d = __shfl_xor(v, 48);
  return (v + a) + (b + d);
}

// Relaxed workgroup barrier: orders LDS (lgkm), leaves global loads in flight.
__device__ __forceinline__ void wg_barrier_lds() {
  __builtin_amdgcn_sched_barrier(0);
  asm volatile("s_waitcnt lgkmcnt(0)" ::: "memory");
  __builtin_amdgcn_s_barrier();
  __builtin_amdgcn_sched_barrier(0);
}

__device__ __forceinline__ void gl_lds16(const half_t* g, half_t* l) {
  __builtin_amdgcn_global_load_lds(
      (__attribute__((address_space(1))) void*)(void*)g,
      (__attribute__((address_space(3))) void*)(void*)l, 16, 0, 0);
}

// ---------------- cvt kernels (unchanged, verified) ----------------
__global__ void cw_cvt_x(const float* __restrict__ X, half_t* __restrict__ Xh, long n4) {
  long i = (long)blockIdx.x * blockDim.x + threadIdx.x;
  const long stride = (long)gridDim.x * blockDim.x;
  const float4* X4 = (const float4*)X;
  h2* out2 = (h2*)Xh;
  for (; i < n4; i += stride) {
    float4 v = X4[i];
    h2 a; a[0] = (half_t)v.x; a[1] = (half_t)v.y;
    h2 b; b[0] = (half_t)v.z; b[1] = (half_t)v.w;
    out2[2 * i] = a;
    out2[2 * i + 1] = b;
  }
}

__global__ void cw_cvt_wt(const float* __restrict__ W, half_t* __restrict__ WT) {
  int idx = blockIdx.x * 256 + threadIdx.x;  // 131072 total
  int o = idx >> 8, d = idx & 255;
  WT[idx] = (half_t)W[d * 512 + o];
}

// ---------------- x projection (unchanged, verified) ----------------
__global__ __launch_bounds__(256) void cw_xproj(const half_t* __restrict__ Xh,
                                                const half_t* __restrict__ WT,
                                                const float* __restrict__ bias,
                                                half_t* __restrict__ xout) {
  const int mod = blockIdx.y;
  const int Ti = 2048 >> mod;
  const long Mi = (long)64 * Ti;
  const long m0r = (long)blockIdx.x * 256;
  if (m0r >= Mi) return;
  __shared__ alignas(16) half_t Bs[64 * 256];
  __shared__ alignas(16) half_t As[256 * 64];
  const int tid = threadIdx.x;
  const int wv = tid >> 6, l = tid & 63;
  const int lr = l & 15, lk = (l >> 4) * 8;
  const int shf = 11 - mod;

#pragma unroll
  for (int it = 0; it < 8; ++it) {
    int slot = it * 256 + tid;
    int n = slot >> 5, kc = slot & 31;
    gl_lds16(WT + ((mod << 6) + n) * 256 + kc * 8, Bs + slot * 8);
  }

  f4 acc[4][4];
#pragma unroll
  for (int a = 0; a < 4; ++a)
#pragma unroll
    for (int bq = 0; bq < 4; ++bq) acc[a][bq] = f4{0.f, 0.f, 0.f, 0.f};

  for (int kt = 0; kt < 4; ++kt) {
#pragma unroll
    for (int it = 0; it < 8; ++it) {
      int slot = it * 256 + tid;
      int r = slot >> 3, kc = slot & 7;
      long m = m0r + r;
      long g = (m >> shf) * 2048 + ((m & (long)(Ti - 1)) << mod);
      gl_lds16(Xh + g * 256 + kt * 64 + kc * 8, As + slot * 8);
    }
    __syncthreads();
#pragma unroll
    for (int ks = 0; ks < 2; ++ks) {
      h8 af[4], bf[4];
#pragma unroll
      for (int mi = 0; mi < 4; ++mi)
        af[mi] = *(const h8*)&As[(wv * 64 + mi * 16 + lr) * 64 + ks * 32 + lk];
#pragma unroll
      for (int ni = 0; ni < 4; ++ni)
        bf[ni] = *(const h8*)&Bs[(ni * 16 + lr) * 256 + kt * 64 + ks * 32 + lk];
#pragma unroll
      for (int mi = 0; mi < 4; ++mi)
#pragma unroll
        for (int ni = 0; ni < 4; ++ni)
          acc[mi][ni] = __builtin_amdgcn_mfma_f32_16x16x32_f16(af[mi], bf[ni], acc[mi][ni], 0, 0, 0);
    }
    __syncthreads();
  }

  const long xb = 16777216L - (16777216L >> mod);
#pragma unroll
  for (int ni = 0; ni < 4; ++ni) {
    int n = ni * 16 + lr;
    float bv = bias[(mod << 6) + n];
#pragma unroll
    for (int mi = 0; mi < 4; ++mi) {
      f4 cf = acc[mi][ni];
#pragma unroll
      for (int q = 0; q < 4; ++q) {
        long m = m0r + wv * 64 + mi * 16 + (l >> 4) * 4 + q;
        xout[xb + m * 64 + n] = (half_t)(cf[q] + bv);
      }
    }
  }
}

// ---------------- scan round 11 ----------------
// PAIR p: fast module m_p (period 2^p) on waves {2p,2p+1}; slow module
// S[p] = {m6,m5,m4,m7}[p]. Per lane: 2 cols {colA=32*half+cl, colB=colA+16},
// K-chunk q=l>>4. Owners: l<32 -> fast col ownCol; l>=32 -> slow col ownCol.

template <int PAIR>
__device__ __forceinline__ void scan_role(
    const unsigned short* __restrict__ xb16,
    const float* __restrict__ Wf, const float* __restrict__ Ws,
    float* __restrict__ out, half_t (*hbuf)[512], int b) {
  constexpr int P4Fv[4] = {64, 56, 48, 40};
  constexpr int HBFv[4] = {0, 32, 64, 96};
  constexpr int P4Sv[4] = {16, 24, 32, 8};
  constexpr int HBSv[4] = {192, 160, 128, 224};
  constexpr int SSHv[4] = {6, 5, 4, 7};
  constexpr long FXBv[4] = {0L, 8388608L, 12582912L, 14680064L};
  constexpr long SXBv[4] = {16515072L, 16252928L, 15728640L, 16646144L};
  constexpr int FBASEv[4] = {0, 64, 128, 192};
  constexpr int SBASEv[4] = {384, 320, 256, 448};
  constexpr int P4F = P4Fv[PAIR], HBF = HBFv[PAIR];
  constexpr int P4S = P4Sv[PAIR], HBS = HBSv[PAIR], SSH = SSHv[PAIR];
  constexpr int FB = FBASEv[PAIR], SB = SBASEv[PAIR];
  constexpr int SROWS = 2048 >> SSH;
  constexpr int SMASK = (1 << SSH) - 1;

  const int tid = threadIdx.x;
  const int wv = tid >> 6, l = tid & 63;
  const int half = wv & 1;
  const int q = l >> 4;
  const int cl = l & 15;
  const int colA = 32 * half + cl;
  const int colB = colA + 16;
  const int sg01 = q & 1;
  const bool ownFast = (l < 32);
  const int ownCol = 32 * half + 16 * sg01 + cl;

  // ---- weights (all registers, static indices) ----
  h2 wfA[P4F], wfB[P4F], wsA[P4S], wsB[P4S];
  if constexpr (PAIR == 0) {
    // m0 bank-rotation (R4-verified): wf*[4g+j] <- pair q*64+((g+2q)&15)*4+j
#pragma unroll
    for (int g = 0; g < 16; ++g) {
      const int gg = (g + 2 * q) & 15;
#pragma unroll
      for (int j = 0; j < 4; ++j) {
        int pr = (q << 6) + gg * 4 + j;
        wfA[g * 4 + j] = h2{(half_t)Wf[(2 * pr) * 64 + colA], (half_t)Wf[(2 * pr + 1) * 64 + colA]};
        wfB[g * 4 + j] = h2{(half_t)Wf[(2 * pr) * 64 + colB], (half_t)Wf[(2 * pr + 1) * 64 + colB]};
      }
    }
  } else {
#pragma unroll
    for (int p = 0; p < P4F; ++p) {
      int pr = q * P4F + p;
      wfA[p] = h2{(half_t)Wf[(2 * pr) * 64 + colA], (half_t)Wf[(2 * pr + 1) * 64 + colA]};
      wfB[p] = h2{(half_t)Wf[(2 * pr) * 64 + colB], (half_t)Wf[(2 * pr + 1) * 64 + colB]};
    }
  }
#pragma unroll
  for (int p = 0; p < P4S; ++p) {
    int pr = q * P4S + p;
    wsA[p] = h2{(half_t)Ws[(2 * pr) * 64 + colA], (half_t)Ws[(2 * pr + 1) * 64 + colA]};
    wsB[p] = h2{(half_t)Ws[(2 * pr) * 64 + colB], (half_t)Ws[(2 * pr + 1) * 64 + colB]};
  }

  hbuf[0][tid] = (half_t)0.f;
  hbuf[1][tid] = (half_t)0.f;

  // ---- owner x pointer (fast owners: module m_PAIR; slow owners: S[PAIR]) ----
  const unsigned short* xp = ownFast
      ? (xb16 + FXBv[PAIR] + ((long)b << (17 - PAIR)) + ownCol)
      : (xb16 + SXBv[PAIR] + ((long)b << (17 - SSH)) + ownCol);

  unsigned short xr0 = 0, xr1 = 0, xr2 = 0, xr3 = 0, xrS = 0;
  if (ownFast) {
    xr0 = xp[0];
    if constexpr (PAIR == 0) { xr1 = xp[64]; xr2 = xp[128]; xr3 = xp[192]; }
    if constexpr (PAIR == 1) { xr1 = xp[64]; }
  } else {
    xrS = xp[0];
  }
  float hs = 0.f;
  __syncthreads();

  auto stepf = [&](auto offc, int t, const half_t* hin, half_t* hout) {
    constexpr int OFF = decltype(offc)::value;
    const h2* hin2 = (const h2*)hin;
    constexpr bool FACT = (PAIR == 0) || (PAIR == 1 && (OFF & 1) == 0) ||
                          (PAIR >= 2 && OFF == 0);
    float vA = 0.f, vB = 0.f, vSA = 0.f, vSB = 0.f;
    bool fup = false;
    if constexpr (FACT) {
      if constexpr (PAIR == 3) fup = ((t & 7) == 0);
      else fup = true;
      if (fup) {
        float a0 = 0.f, a1 = 0.f, a2 = 0.f, a3 = 0.f;
        float b0 = 0.f, b1 = 0.f, b2 = 0.f, b3 = 0.f;
        if constexpr (PAIR == 0) {
          const h2* hp = hin2 + (q << 6);
#pragma unroll
          for (int g = 0; g < 16; ++g) {
            const int gg = (g + 2 * q) & 15;  // runtime LDS index only
            h2 h0 = hp[gg * 4 + 0], h1 = hp[gg * 4 + 1];
            h2 h2v = hp[gg * 4 + 2], h3 = hp[gg * 4 + 3];
            a0 = dot2f(h0, wfA[g * 4 + 0], a0); b0 = dot2f(h0, wfB[g * 4 + 0], b0);
            a1 = dot2f(h1, wfA[g * 4 + 1], a1); b1 = dot2f(h1, wfB[g * 4 + 1], b1);
            a2 = dot2f(h2v, wfA[g * 4 + 2], a2); b2 = dot2f(h2v, wfB[g * 4 + 2], b2);
            a3 = dot2f(h3, wfA[g * 4 + 3], a3); b3 = dot2f(h3, wfB[g * 4 + 3], b3);
          }
        } else {
          const h2* hp = hin2 + HBF + q * P4F;
#pragma unroll
          for (int p = 0; p < P4F; p += 4) {
            h2 h0 = hp[p], h1 = hp[p + 1], h2v = hp[p + 2], h3 = hp[p + 3];
            a0 = dot2f(h0, wfA[p + 0], a0); b0 = dot2f(h0, wfB[p + 0], b0);
            a1 = dot2f(h1, wfA[p + 1], a1); b1 = dot2f(h1, wfB[p + 1], b1);
            a2 = dot2f(h2v, wfA[p + 2], a2); b2 = dot2f(h2v, wfB[p + 2], b2);
            a3 = dot2f(h3, wfA[p + 3], a3); b3 = dot2f(h3, wfB[p + 3], b3);
          }
        }
        vA = red3((a0 + a1) + (a2 + a3));
        vB = red3((b0 + b1) + (b2 + b3));
      }
    }
    bool sup = false;
    if constexpr (OFF == 0) {
      sup = ((t & SMASK) == 0);
      if (sup) {
        float a0 = 0.f, a1 = 0.f, a2 = 0.f, a3 = 0.f;
        float b0 = 0.f, b1 = 0.f, b2 = 0.f, b3 = 0.f;
        const h2* hp = hin2 + HBS + q * P4S;
#pragma unroll
        for (int p = 0; p < P4S; p += 4) {
          h2 h0 = hp[p], h1 = hp[p + 1], h2v = hp[p + 2], h3 = hp[p + 3];
          a0 = dot2f(h0, wsA[p + 0], a0); b0 = dot2f(h0, wsB[p + 0], b0);
          a1 = dot2f(h1, wsA[p + 1], a1); b1 = dot2f(h1, wsB[p + 1], b1);
          a2 = dot2f(h2v, wsA[p + 2], a2); b2 = dot2f(h2v, wsB[p + 2], b2);
          a3 = dot2f(h3, wsA[p + 3], a3); b3 = dot2f(h3, wsB[p + 3], b3);
        }
        vSA = red3((a0 + a1) + (a2 + a3));
        vSB = red3((b0 + b1) + (b2 + b3));
      }
    }
    // ---- owner phase: 1 col per lane ----
    bool myUpd = ownFast ? fup : sup;
    float mySum = ownFast ? (sg01 ? vB : vA) : (sg01 ? vSB : vSA);
    float xv;
    if (ownFast) {
      if constexpr (PAIR == 0) {
        if constexpr (OFF == 0) xv = u2f(xr0);
        else if constexpr (OFF == 1) xv = u2f(xr1);
        else if constexpr (OFF == 2) xv = u2f(xr2);
        else xv = u2f(xr3);
      } else if constexpr (PAIR == 1) {
        xv = (OFF == 0) ? u2f(xr0) : u2f(xr1);
      } else {
        xv = u2f(xr0);
      }
    } else {
      xv = u2f(xrS);
    }
    float s = myUpd ? (mySum + xv) : hs;
    hs = fast_tanh(s);
    hout[(ownFast ? FB : SB) + ownCol] = (half_t)hs;
    // ---- ring advance (raw u16; cvt at use) ----
    if (ownFast) {
      if constexpr (PAIR == 0) {
        int tn = t + OFF + 4;
        if (tn < 2048) {
          unsigned short nv = xp[(long)tn << 6];
          if constexpr (OFF == 0) xr0 = nv;
          else if constexpr (OFF == 1) xr1 = nv;
          else if constexpr (OFF == 2) xr2 = nv;
          else xr3 = nv;
        }
      } else if constexpr (PAIR == 1) {
        if constexpr (OFF == 0) {
          int rn = (t >> 1) + 2;
          if (rn < 1024) xr0 = xp[(long)rn << 6];
        } else if constexpr (OFF == 2) {
          int rn = (t >> 1) + 3;
          if (rn < 1024) xr1 = xp[(long)rn << 6];
        }
      } else if constexpr (PAIR == 2) {
        if constexpr (OFF == 0) {
          int ni = (t >> 2) + 1;
          if (ni < 512) xr0 = xp[(long)ni << 6];
        }
      } else {
        if constexpr (OFF == 0) {
          if (fup) {
            int ni = (t >> 3) + 1;
            if (ni < 256) xr0 = xp[(long)ni << 6];
          }
        }
      }
    } else {
      if (sup) {
        int ni = (t >> SSH) + 1;
        if (ni < SROWS) xrS = xp[(long)ni << 6];
      }
    }
    wg_barrier_lds();
  };

  for (int t = 0; t < 2048; t += 4) {
    stepf(std::integral_constant<int, 0>{}, t, hbuf[0], hbuf[1]);
    stepf(std::integral_constant<int, 1>{}, t, hbuf[1], hbuf[0]);
    stepf(std::integral_constant<int, 2>{}, t, hbuf[0], hbuf[1]);
    stepf(std::integral_constant<int, 3>{}, t, hbuf[1], hbuf[0]);
  }

  out[((long)b << 9) + (ownFast ? FB : SB) + ownCol] = hs;
}

__global__ __launch_bounds__(512, 2) void cw_scan11(
    const half_t* __restrict__ xbuf,
    const float* __restrict__ Wc0, const float* __restrict__ Wc1,
    const float* __restrict__ Wc2, const float* __restrict__ Wc3,
    const float* __restrict__ Wc4, const float* __restrict__ Wc5,
    const float* __restrict__ Wc6, const float* __restrict__ Wc7,
    float* __restrict__ out) {
  __shared__ alignas(16) half_t hbuf[2][512];
  const int b = blockIdx.x;
  const unsigned short* xb16 = (const unsigned short*)xbuf;
  const int pair = threadIdx.x >> 7;  // wave>>1
  if (pair == 0) scan_role<0>(xb16, Wc0, Wc6, out, hbuf, b);
  else if (pair == 1) scan_role<1>(xb16, Wc1, Wc5, out, hbuf, b);
  else if (pair == 2) scan_role<2>(xb16, Wc2, Wc4, out, hbuf, b);
  else scan_role<3>(xb16, Wc3, Wc7, out, hbuf, b);
}

// ---------------- launcher ----------------
extern "C" void kernel_launch(void* const* d_in, const int* in_sizes, int n_in,
                              void* d_out, int out_size, void* d_ws, size_t ws_size,
                              hipStream_t stream) {
  const float* X = (const float*)d_in[0];
  const float* W = (const float*)d_in[1];
  const float* bias = (const float*)d_in[2];
  const float* Wc0 = (const float*)d_in[3];
  const float* Wc1 = (const float*)d_in[4];
  const float* Wc2 = (const float*)d_in[5];
  const float* Wc3 = (const float*)d_in[6];
  const float* Wc4 = (const float*)d_in[7];
  const float* Wc5 = (const float*)d_in[8];
  const float* Wc6 = (const float*)d_in[9];
  const float* Wc7 = (const float*)d_in[10];
  float* out = (float*)d_out;

  half_t* Xh = (half_t*)d_ws;                       // 67,108,864 B
  half_t* WT = (half_t*)((char*)d_ws + 67108864);   //    262,144 B
  half_t* xbuf = (half_t*)((char*)d_ws + 67371008); // 33,423,360 B

  cw_cvt_x<<<4096, 256, 0, stream>>>(X, Xh, 8388608L);
  cw_cvt_wt<<<512, 256, 0, stream>>>(W, WT);
  dim3 g(512, 8);
  cw_xproj<<<g, 256, 0, stream>>>(Xh, WT, bias, xbuf);
  cw_scan11<<<64, 512, 0, stream>>>(xbuf, Wc0, Wc1, Wc2, Wc3, Wc4, Wc5, Wc6, Wc7, out);
}